// Round 1
// baseline (88.433 us; speedup 1.0000x reference)
//
#include <hip/hip_runtime.h>
#include <hip/hip_bf16.h>
#include <math.h>

#define HH 4
#define DD 64
#define BS 32

__device__ __forceinline__ float silu_f(float x) {
    return x / (1.0f + __expf(-x));
}

// Kernel A: per-compressed-block mean of k and v.
// grid = maxC blocks (upper bound on total compressed blocks), 256 threads (h = tid>>6, d = tid&63)
__global__ void hstu_cmp_means(const float* __restrict__ k, const float* __restrict__ v,
                               const int* __restrict__ offsets, int B,
                               float* __restrict__ k_cmp, float* __restrict__ v_cmp) {
    int c = blockIdx.x;
    int acc = 0, b = -1, jc = 0;
    for (int bb = 0; bb < B; ++bb) {
        int len = offsets[bb + 1] - offsets[bb];
        int nb = (len + BS - 1) >> 5;
        if (b < 0 && c < acc + nb) { b = bb; jc = c - acc; }
        acc += nb;
    }
    if (b < 0) return;  // c >= total compressed blocks
    int t0 = offsets[b] + jc * BS;
    int cnt = offsets[b + 1] - t0;
    if (cnt > BS) cnt = BS;

    int h = threadIdx.x >> 6;
    int d = threadIdx.x & 63;
    float ks = 0.f, vs = 0.f;
    for (int i = 0; i < cnt; ++i) {
        ks += k[((size_t)(t0 + i) * HH + h) * DD + d];
        vs += v[((size_t)(t0 + i) * HH + h) * DD + d];
    }
    float inv = 1.0f / (float)cnt;
    k_cmp[((size_t)c * HH + h) * DD + d] = ks * inv;
    v_cmp[((size_t)c * HH + h) * DD + d] = vs * inv;
}

// Kernel B: one block per token t, one wave (64 lanes) per head.
__global__ __launch_bounds__(256) void hstu_main(
    const float* __restrict__ q, const float* __restrict__ k, const float* __restrict__ v,
    const float* __restrict__ g_cmp, const float* __restrict__ g_slc,
    const int* __restrict__ offsets, int B,
    const float* __restrict__ k_cmp, const float* __restrict__ v_cmp,
    float* __restrict__ o_cmp, float* __restrict__ o_slc) {
    int t = blockIdx.x;
    int h = threadIdx.x >> 6;
    int lane = threadIdx.x & 63;

    __shared__ float q_s[HH][DD];

    // find batch b: offsets[b] <= t < offsets[b+1]
    int b = 0;
    while (b + 1 < B && t >= offsets[b + 1]) ++b;
    int seq_start = offsets[b];
    int p = t - seq_start;       // local position
    int q_blk = p >> 5;          // causal: compressed blocks j <= q_blk

    // base compressed-block offset for this sequence
    int base_cmp = 0;
    for (int bb = 0; bb < b; ++bb) {
        int len = offsets[bb + 1] - offsets[bb];
        base_cmp += (len + BS - 1) >> 5;
    }

    float qd = q[((size_t)t * HH + h) * DD + lane];
    q_s[h][lane] = qd;
    __syncthreads();

    int j = lane >> 2, g = lane & 3;
    const float* qrow = q_s[h];

    // ---- scores over compressed blocks: lane (j,g) does 16-elem partial dot ----
    float part = 0.f;
    if (j <= q_blk) {
        const float* kr = k_cmp + ((size_t)(base_cmp + j) * HH + h) * DD + g * 16;
        #pragma unroll
        for (int x = 0; x < 16; ++x) part += qrow[g * 16 + x] * kr[x];
    }
    part += __shfl_xor(part, 1);
    part += __shfl_xor(part, 2);
    float s = part * 0.125f;  // D^-0.5

    // broadcast all 16 scores to every lane (fully unrolled -> registers)
    float sc[16];
    #pragma unroll
    for (int jj = 0; jj < 16; ++jj) sc[jj] = __shfl(s, jj << 2);

    // ---- o_cmp = sum_j silu(sc[j]) * v_cmp[j] * g_cmp ----
    float acc = 0.f;
    #pragma unroll
    for (int jj = 0; jj < 16; ++jj) {
        if (jj <= q_blk) {
            float pj = silu_f(sc[jj]);
            acc += pj * v_cmp[((size_t)(base_cmp + jj) * HH + h) * DD + lane];
        }
    }
    acc *= g_cmp[(size_t)t * HH + h];
    o_cmp[((size_t)t * HH + h) * DD + lane] = acc;

    // ---- top-4 causal blocks by score (ties -> lowest index, matches lax.top_k) ----
    int sels[4];
    unsigned taken = 0;
    #pragma unroll
    for (int r = 0; r < 4; ++r) {
        float best = -INFINITY;
        int bi = -1;
        #pragma unroll
        for (int jj = 0; jj < 16; ++jj) {
            bool cand = (jj <= q_blk) && !((taken >> jj) & 1u);
            if (cand && sc[jj] > best) { best = sc[jj]; bi = jj; }
        }
        sels[r] = bi;
        if (bi >= 0) taken |= (1u << bi);
    }

    // ---- o_slc: token-level attention within selected blocks ----
    float acc2 = 0.f;
    #pragma unroll
    for (int r = 0; r < 4; ++r) {
        int bsel = sels[r];
        if (bsel < 0) continue;
        int ibase = bsel * BS;
        int lim = p - ibase + 1;     // number of causal tokens in this block (>=1)
        if (lim > BS) lim = BS;
        #pragma unroll
        for (int pass = 0; pass < 2; ++pass) {
            if (pass * 16 < lim) {   // wave-uniform
                int i = pass * 16 + j;
                float pt = 0.f;
                if (i < lim) {
                    const float* kr = k + ((size_t)(seq_start + ibase + i) * HH + h) * DD + g * 16;
                    #pragma unroll
                    for (int x = 0; x < 16; ++x) pt += qrow[g * 16 + x] * kr[x];
                }
                pt += __shfl_xor(pt, 1);
                pt += __shfl_xor(pt, 2);
                float ss = pt * 0.125f;
                float ps = (i < lim) ? silu_f(ss) : 0.f;
                #pragma unroll
                for (int ii = 0; ii < 16; ++ii) {
                    int it = pass * 16 + ii;
                    float pv = __shfl(ps, ii << 2);
                    if (it < lim) {  // wave-uniform; also guards OOB on last sequence
                        acc2 += pv * v[((size_t)(seq_start + ibase + it) * HH + h) * DD + lane];
                    }
                }
            }
        }
    }
    acc2 *= g_slc[(size_t)t * HH + h];
    o_slc[((size_t)t * HH + h) * DD + lane] = acc2;
}

extern "C" void kernel_launch(void* const* d_in, const int* in_sizes, int n_in,
                              void* d_out, int out_size, void* d_ws, size_t ws_size,
                              hipStream_t stream) {
    const float* q     = (const float*)d_in[0];
    const float* k     = (const float*)d_in[1];
    const float* v     = (const float*)d_in[2];
    const float* g_cmp = (const float*)d_in[3];
    const float* g_slc = (const float*)d_in[4];
    const int*   offs  = (const int*)d_in[5];

    int T = in_sizes[0] / (HH * DD);
    int B = in_sizes[5] - 1;
    int maxC = (T + BS - 1) / BS + B;  // upper bound on total compressed blocks

    float* k_cmp = (float*)d_ws;
    float* v_cmp = (float*)d_ws + (size_t)maxC * HH * DD;
    float* o_cmp = (float*)d_out;
    float* o_slc = (float*)d_out + (size_t)T * HH * DD;

    hipLaunchKernelGGL(hstu_cmp_means, dim3(maxC), dim3(256), 0, stream,
                       k, v, offs, B, k_cmp, v_cmp);
    hipLaunchKernelGGL(hstu_main, dim3(T), dim3(256), 0, stream,
                       q, k, v, g_cmp, g_slc, offs, B, k_cmp, v_cmp, o_cmp, o_slc);
}

// Round 2
// 60.681 us; speedup vs baseline: 1.4573x; 1.4573x over previous
//
#include <hip/hip_runtime.h>
#include <math.h>

#define HH 4
#define DD 64
#define BS 32

__device__ __forceinline__ float silu_f(float x) {
    return x / (1.0f + __expf(-x));
}

// Kernel A: per-compressed-block mean of k and v.
// grid = maxC, 256 threads = (h,d) flat. Fast path cnt==32 fully unrolled (MLP).
__global__ void hstu_cmp_means(const float* __restrict__ k, const float* __restrict__ v,
                               const int* __restrict__ offsets, int B,
                               float* __restrict__ k_cmp, float* __restrict__ v_cmp) {
    int c = blockIdx.x;
    int acc = 0, b = -1, jc = 0;
    for (int bb = 0; bb < B; ++bb) {
        int len = offsets[bb + 1] - offsets[bb];
        int nb = (len + BS - 1) >> 5;
        if (b < 0 && c < acc + nb) { b = bb; jc = c - acc; }
        acc += nb;
    }
    if (b < 0) return;
    int t0 = offsets[b] + jc * BS;
    int cnt = offsets[b + 1] - t0;
    if (cnt > BS) cnt = BS;

    int hd = threadIdx.x;  // 0..255 over (h,d), coalesced
    const float* kp = k + (size_t)t0 * (HH * DD) + hd;
    const float* vp = v + (size_t)t0 * (HH * DD) + hd;
    float ks = 0.f, vs = 0.f;
    if (cnt == BS) {
        #pragma unroll
        for (int i = 0; i < BS; ++i) { ks += kp[i * (HH * DD)]; vs += vp[i * (HH * DD)]; }
    } else {
        for (int i = 0; i < cnt; ++i) { ks += kp[i * (HH * DD)]; vs += vp[i * (HH * DD)]; }
    }
    float inv = 1.0f / (float)cnt;
    k_cmp[(size_t)c * (HH * DD) + hd] = ks * inv;
    v_cmp[(size_t)c * (HH * DD) + hd] = vs * inv;
}

// Kernel B: one block per token t, one wave per head.
__global__ __launch_bounds__(256) void hstu_main(
    const float* __restrict__ q, const float* __restrict__ k, const float* __restrict__ v,
    const float* __restrict__ g_cmp, const float* __restrict__ g_slc,
    const int* __restrict__ offsets, int B,
    const float* __restrict__ k_cmp, const float* __restrict__ v_cmp,
    float* __restrict__ o_cmp, float* __restrict__ o_slc) {
    int t = blockIdx.x;
    int h = threadIdx.x >> 6;
    int lane = threadIdx.x & 63;

    __shared__ __align__(16) float q_s[HH][DD];
    __shared__ float p_lds[HH][BS];

    int b = 0;
    while (b + 1 < B && t >= offsets[b + 1]) ++b;
    int seq_start = offsets[b];
    int p = t - seq_start;
    int q_blk = p >> 5;
    int base_cmp = 0;
    for (int bb = 0; bb < b; ++bb)
        base_cmp += (offsets[bb + 1] - offsets[bb] + BS - 1) >> 5;

    q_s[h][lane] = q[((size_t)t * HH + h) * DD + lane];
    __syncthreads();  // uniform, once; cheap

    // ---- Phase A: compressed-block scores. lane=(j,g4): j<16 blocks, 4 lanes x 16 elems ----
    int j = lane >> 2, g4 = lane & 3;
    float part = 0.f;
    if (j <= q_blk) {
        const float4* kr = (const float4*)(k_cmp + ((size_t)(base_cmp + j) * HH + h) * DD + g4 * 16);
        const float4* qv = (const float4*)(&q_s[h][g4 * 16]);
        #pragma unroll
        for (int x = 0; x < 4; ++x) {
            float4 kk = kr[x]; float4 qq = qv[x];
            part += qq.x * kk.x + qq.y * kk.y + qq.z * kk.z + qq.w * kk.w;
        }
    }
    part += __shfl_xor(part, 1);
    part += __shfl_xor(part, 2);
    float s_own = part * 0.125f;
    float p_own = (j <= q_blk) ? silu_f(s_own) : 0.f;  // one exp per lane

    float sc[16], pc[16];
    #pragma unroll
    for (int jj = 0; jj < 16; ++jj) {
        sc[jj] = __shfl(s_own, jj << 2);
        pc[jj] = __shfl(p_own, jj << 2);
    }

    // ---- Phase B: o_cmp. lane = d ----
    float acc = 0.f;
    #pragma unroll
    for (int jj = 0; jj < 16; ++jj) {
        if (jj <= q_blk)  // wave-uniform
            acc += pc[jj] * v_cmp[((size_t)(base_cmp + jj) * HH + h) * DD + lane];
    }
    acc *= g_cmp[(size_t)t * HH + h];
    o_cmp[((size_t)t * HH + h) * DD + lane] = acc;

    // ---- top-4 (ties -> lowest index, matches lax.top_k) ----
    int sels[4];
    unsigned taken = 0;
    #pragma unroll
    for (int r = 0; r < 4; ++r) {
        float best = -INFINITY;
        int bi = -1;
        #pragma unroll
        for (int jj = 0; jj < 16; ++jj) {
            bool cand = (jj <= q_blk) && !((taken >> jj) & 1u);
            if (cand && sc[jj] > best) { best = sc[jj]; bi = jj; }
        }
        sels[r] = bi;
        if (bi >= 0) taken |= (1u << bi);
    }

    // ---- Phase C: o_slc over selected blocks ----
    int gh = lane >> 5, i32 = lane & 31;   // QK split: 2 halves x 32 tokens
    int tg = lane >> 4, dg = lane & 15;    // PV split: 4 token-groups x 16 d-quads
    const float4* qh = (const float4*)(&q_s[h][gh * 32]);
    float4 acc2 = make_float4(0.f, 0.f, 0.f, 0.f);

    #pragma unroll
    for (int r = 0; r < 4; ++r) {
        int bsel = sels[r];
        if (bsel < 0) continue;           // wave-uniform
        int ibase = bsel * BS;
        int lim = p - ibase + 1;          // causal tokens in block, >=1
        if (lim > BS) lim = BS;

        // QK: all 32 token-dots in one pass (lane = half x token)
        float pt = 0.f;
        if (i32 < lim) {
            const float4* kr = (const float4*)(k + ((size_t)(seq_start + ibase + i32) * HH + h) * DD + gh * 32);
            #pragma unroll
            for (int x = 0; x < 8; ++x) {
                float4 kk = kr[x]; float4 qq = qh[x];
                pt += qq.x * kk.x + qq.y * kk.y + qq.z * kk.z + qq.w * kk.w;
            }
        }
        pt += __shfl_xor(pt, 32);
        float ps = (i32 < lim) ? silu_f(pt * 0.125f) : 0.f;
        if (lane < BS) p_lds[h][lane] = ps;
        __builtin_amdgcn_wave_barrier();  // keep write->read order (intra-wave, in-order DS)

        // PV: lane=(tg,dg): 8 iters x {LDS broadcast p, float4 v load, 4 FMA}
        #pragma unroll
        for (int m = 0; m < 8; ++m) {
            int it = m * 4 + tg;
            if (it < lim) {
                float pv = p_lds[h][it];
                float4 vv = *(const float4*)(v + ((size_t)(seq_start + ibase + it) * HH + h) * DD + dg * 4);
                acc2.x += pv * vv.x; acc2.y += pv * vv.y;
                acc2.z += pv * vv.z; acc2.w += pv * vv.w;
            }
        }
        __builtin_amdgcn_wave_barrier();
    }

    // reduce across the 4 token-groups
    acc2.x += __shfl_xor(acc2.x, 16); acc2.x += __shfl_xor(acc2.x, 32);
    acc2.y += __shfl_xor(acc2.y, 16); acc2.y += __shfl_xor(acc2.y, 32);
    acc2.z += __shfl_xor(acc2.z, 16); acc2.z += __shfl_xor(acc2.z, 32);
    acc2.w += __shfl_xor(acc2.w, 16); acc2.w += __shfl_xor(acc2.w, 32);

    if (tg == 0) {
        float gs = g_slc[(size_t)t * HH + h];
        float4 o = make_float4(acc2.x * gs, acc2.y * gs, acc2.z * gs, acc2.w * gs);
        *(float4*)(o_slc + ((size_t)t * HH + h) * DD + dg * 4) = o;
    }
}

extern "C" void kernel_launch(void* const* d_in, const int* in_sizes, int n_in,
                              void* d_out, int out_size, void* d_ws, size_t ws_size,
                              hipStream_t stream) {
    const float* q     = (const float*)d_in[0];
    const float* k     = (const float*)d_in[1];
    const float* v     = (const float*)d_in[2];
    const float* g_cmp = (const float*)d_in[3];
    const float* g_slc = (const float*)d_in[4];
    const int*   offs  = (const int*)d_in[5];

    int T = in_sizes[0] / (HH * DD);
    int B = in_sizes[5] - 1;
    int maxC = (T + BS - 1) / BS + B;

    float* k_cmp = (float*)d_ws;
    float* v_cmp = (float*)d_ws + (size_t)maxC * HH * DD;
    float* o_cmp = (float*)d_out;
    float* o_slc = (float*)d_out + (size_t)T * HH * DD;

    hipLaunchKernelGGL(hstu_cmp_means, dim3(maxC), dim3(256), 0, stream,
                       k, v, offs, B, k_cmp, v_cmp);
    hipLaunchKernelGGL(hstu_main, dim3(T), dim3(256), 0, stream,
                       q, k, v, g_cmp, g_slc, offs, B, k_cmp, v_cmp, o_cmp, o_slc);
}